// Round 4
// baseline (380.046 us; speedup 1.0000x reference)
//
#include <hip/hip_runtime.h>

// DeformMaxPool2d: B=16, C=64, D=256, K=2, S=2, P=0 -> HO=128.
// gather_idx is a PERMUTATION of 0..65535 (verified absmax=0 in R2/R3).
//
// R8 post-mortem chain:
//  - R5: harness re-poisons ws (1 GiB fill ~161us) UNCONDITIONALLY; using ws
//    is free. Fixed reset charge in timed window ~267us.
//  - R6: native ds_max_f32 asm == enc/dec+atomicMax(uint) timing EXACTLY
//    (354.68 vs 354.60) -> scatter VALU is fully hidden. Kernel ~87us vs
//    53us HBM floor (3.85 TB/s achieved; harness fill does 6.6).
//  - R7: FAILED absmax 2.14. Inline-asm DS atomic is opaque to the
//    compiler's waitcnt insertion; restructured schedule exposed the race
//    R6 dodged by luck (+ uninitialized tail prefetch = UB). Lesson: use
//    the intrinsic atomic the compiler understands — it's free anyway.
//  - R8 = R4's PROVEN enc/uint-atomicMax scatter, with the one hypothesis
//    R7 meant to test: NO nontemporal hint on the read path (x, inv); NT
//    only on write-once output stores. UB-free +1-iter prefetch (clamped
//    index; dead tail loads DCE'd). __launch_bounds__(1024,8): VGPR cap 64,
//    64KB LDS -> 2 blocks/CU so HBM stream overlaps DS-atomic burst.

#define D_DIM     256
#define HO        128
#define PLANE_IN  (D_DIM * D_DIM)   // 65536 pixels per plane
#define PLANE_OUT (HO * HO)         // 16384 outputs per plane
#define NPLANES   (16 * 64)         // 1024 (b,c) planes
#define TPB       1024
#define NIT       (PLANE_IN / 4 / TPB)   // 16 main-loop iterations

typedef float          f32x4 __attribute__((ext_vector_type(4)));
typedef unsigned short u16x4 __attribute__((ext_vector_type(4)));

// ---- sortable encoding: monotone float -> uint (handles negatives) ----
__device__ __forceinline__ unsigned int enc_f32(float f) {
    unsigned int b = __float_as_uint(f);
    return (b & 0x80000000u) ? ~b : (b | 0x80000000u);
}
__device__ __forceinline__ float dec_f32(unsigned int u) {
    unsigned int b = (u & 0x80000000u) ? (u & 0x7FFFFFFFu) : ~u;
    return __uint_as_float(b);
}

// ---- prep: inverse permutation, pixel -> output index (bijection covers all
// 65536 slots every launch; ws re-poisoned each iteration so rebuild). ----
__global__ void build_inv_kernel(const int* __restrict__ gidx,
                                 unsigned short* __restrict__ inv) {
    int t = blockIdx.x * blockDim.x + threadIdx.x;  // [0, 16384)
    if (t >= PLANE_OUT) return;
    int4 g = reinterpret_cast<const int4*>(gidx)[t];
    unsigned short o = (unsigned short)t;
    inv[g.x] = o; inv[g.y] = o; inv[g.z] = o; inv[g.w] = o;
}

// ---- main: one workgroup per (b,c) plane, LDS atomic-max scatter ----
__launch_bounds__(TPB, 8)   // VGPR cap 64; 64KB LDS -> 2 blocks/CU resident
__global__ void pool_scatter_kernel(const float* __restrict__ x,
                                    const unsigned short* __restrict__ inv,
                                    float* __restrict__ out) {
    __shared__ unsigned int so[PLANE_OUT];   // 64 KB
    const int tid = threadIdx.x;
    const int bc  = blockIdx.x;

    // 0 is below the encoding of every finite float
    #pragma unroll
    for (int i = tid; i < PLANE_OUT; i += TPB) so[i] = 0u;
    __syncthreads();

    const f32x4* x4  = reinterpret_cast<const f32x4*>(x + (size_t)bc * PLANE_IN);
    const u16x4* iv4 = reinterpret_cast<const u16x4*>(inv);

    // software-pipelined: iter i+1's loads issue before iter i's atomics.
    // PLAIN loads (no NT hint) — R8's hypothesis: NT read hint cost ~25us BW.
    f32x4 xv = x4[tid];
    u16x4 ov = iv4[tid];
    #pragma unroll
    for (int i = 0; i < NIT; ++i) {
        const int ip = (i + 1 < NIT) ? (i + 1) : i;  // compile-time; tail loads are dead -> DCE
        f32x4 xn = x4[ip * TPB + tid];
        u16x4 on = iv4[ip * TPB + tid];
        atomicMax(&so[ov.x], enc_f32(xv.x));         // ds_max_u32, unconditional
        atomicMax(&so[ov.y], enc_f32(xv.y));
        atomicMax(&so[ov.z], enc_f32(xv.z));
        atomicMax(&so[ov.w], enc_f32(xv.w));
        xv = xn; ov = on;
    }
    __syncthreads();

    // epilogue: decode + coalesced NT (write-once) dwordx4 stores
    f32x4* out4 = reinterpret_cast<f32x4*>(out + (size_t)bc * PLANE_OUT);
    #pragma unroll
    for (int i = tid; i < PLANE_OUT / 4; i += TPB) {
        unsigned int u0 = so[4 * i + 0], u1 = so[4 * i + 1];
        unsigned int u2 = so[4 * i + 2], u3 = so[4 * i + 3];
        f32x4 r = { dec_f32(u0), dec_f32(u1), dec_f32(u2), dec_f32(u3) };
        __builtin_nontemporal_store(r, &out4[i]);
    }
}

// ---- fallback (only if workspace is too small for inv): direct gather ----
__global__ void pool_gather_kernel(const float* __restrict__ x,
                                   const int* __restrict__ gidx,
                                   float* __restrict__ out) {
    long long t = (long long)blockIdx.x * blockDim.x + threadIdx.x;
    if (t >= (long long)NPLANES * PLANE_OUT) return;
    int pos = (int)(t & (PLANE_OUT - 1));
    int bc  = (int)(t >> 14);
    int4 g = reinterpret_cast<const int4*>(gidx)[pos];
    const float* xp = x + (size_t)bc * PLANE_IN;
    float m = fmaxf(fmaxf(xp[g.x], xp[g.y]), fmaxf(xp[g.z], xp[g.w]));
    out[t] = m;
}

extern "C" void kernel_launch(void* const* d_in, const int* in_sizes, int n_in,
                              void* d_out, int out_size, void* d_ws, size_t ws_size,
                              hipStream_t stream) {
    const float* x    = (const float*)d_in[0];
    const int*   gidx = (const int*)d_in[1];
    float*       out  = (float*)d_out;

    if (ws_size >= (size_t)PLANE_IN * sizeof(unsigned short)) {
        unsigned short* inv = (unsigned short*)d_ws;
        build_inv_kernel<<<PLANE_OUT / 256, 256, 0, stream>>>(gidx, inv);
        pool_scatter_kernel<<<NPLANES, TPB, 0, stream>>>(x, inv, out);
    } else {
        long long total = (long long)NPLANES * PLANE_OUT;
        pool_gather_kernel<<<(int)((total + 255) / 256), 256, 0, stream>>>(x, gidx, out);
    }
}